// Round 1
// baseline (810.405 us; speedup 1.0000x reference)
//
#include <hip/hip_runtime.h>
#include <stdint.h>

typedef __attribute__((ext_vector_type(4))) float f32x4;
typedef __attribute__((ext_vector_type(8))) short short8;

#define DEV __device__ __forceinline__

constexpr int Bc = 2, Sc = 2048, Dc = 2048, Hc = 16, HDc = 128;
constexpr int Mc = Bc * Sc;                       // 4096 rows
constexpr float ATTN_SCALE = 0.08838834764831843f; // 1/sqrt(128)

DEV short f2bf(float f) {                         // f32 -> bf16 (RNE)
  unsigned u = __float_as_uint(f);
  unsigned r = (u + 0x7fffu + ((u >> 16) & 1u)) >> 16;
  return (short)(unsigned short)r;
}

// global -> LDS direct copy, 16B per lane. LDS dest must be wave-uniform base;
// HW adds lane*16. Pointers converted via uintptr (CK pattern).
DEV void gload_lds16(const void* gsrc, void* ldst) {
  typedef const __attribute__((address_space(1))) void as1_cvoid;
  typedef __attribute__((address_space(3))) void as3_void;
  __builtin_amdgcn_global_load_lds((as1_cvoid*)(uintptr_t)gsrc,
                                   (as3_void*)(uint32_t)(uintptr_t)ldst,
                                   16, 0, 0);
}

__global__ void cast_f32_bf16(const float* __restrict__ in, short* __restrict__ out, int n8) {
  int i = blockIdx.x * 256 + threadIdx.x;
  if (i >= n8) return;
  f32x4 a = ((const f32x4*)in)[i * 2];
  f32x4 b = ((const f32x4*)in)[i * 2 + 1];
  short8 o;
  o[0] = f2bf(a[0]); o[1] = f2bf(a[1]); o[2] = f2bf(a[2]); o[3] = f2bf(a[3]);
  o[4] = f2bf(b[0]); o[5] = f2bf(b[1]); o[6] = f2bf(b[2]); o[7] = f2bf(b[3]);
  ((short8*)out)[i] = o;
}

__global__ void rope_table(float* __restrict__ ct, float* __restrict__ st) {
  int t = blockIdx.x * 256 + threadIdx.x;   // [0, S*64)
  int s = t >> 6, i = t & 63;
  float freq = powf(10000.0f, -(float)(2 * i) * (1.0f / 128.0f));
  float a = (float)s * freq;
  float sv, cv;
  sincosf(a, &sv, &cv);
  ct[t] = cv; st[t] = sv;
}

// C[m][n] = sum_k A[m][k] * W[n][k]   (NT GEMM; both frags identical K-contiguous loads)
// ROPE: apply rotary to output cols (pairs 2i,2i+1 are adjacent lanes -> shfl_xor 1)
// RESHAPE: store bf16 to [B,H,S,HD]; else f32 row-major [M,D]
template <int ROPE, int RESHAPE>
__global__ __launch_bounds__(256) void gemm_nt(
    const short* __restrict__ A, const short* __restrict__ W,
    short* __restrict__ outb, float* __restrict__ outf,
    const float* __restrict__ ct, const float* __restrict__ st) {
  constexpr int K = Dc;
  __shared__ short Al[128 * 32];
  __shared__ short Bl[128 * 32];
  const int tid = threadIdx.x, lane = tid & 63, w = tid >> 6;
  const int g = lane >> 4, c = lane & 15;
  const int wr = w >> 1, wc = w & 1;
  const int m0 = blockIdx.y * 128, n0 = blockIdx.x * 128;

  f32x4 acc[4][4] = {};

  const int cid = w * 64 + lane;          // 16B chunk id within [128][32] tile
  const short* a0 = A + (size_t)(m0 + (cid >> 2)) * K + (cid & 3) * 8;
  const short* a1 = A + (size_t)(m0 + 64 + (cid >> 2)) * K + (cid & 3) * 8;
  const short* b0 = W + (size_t)(n0 + (cid >> 2)) * K + (cid & 3) * 8;
  const short* b1 = W + (size_t)(n0 + 64 + (cid >> 2)) * K + (cid & 3) * 8;
  char* lA0 = (char*)Al + w * 1024;
  char* lA1 = (char*)Al + 4096 + w * 1024;
  char* lB0 = (char*)Bl + w * 1024;
  char* lB1 = (char*)Bl + 4096 + w * 1024;

  for (int kt = 0; kt < K / 32; ++kt) {
    const int ko = kt * 32;
    gload_lds16(a0 + ko, lA0);
    gload_lds16(a1 + ko, lA1);
    gload_lds16(b0 + ko, lB0);
    gload_lds16(b1 + ko, lB1);
    __syncthreads();
    short8 af[4], wf[4];
#pragma unroll
    for (int fi = 0; fi < 4; ++fi)
      af[fi] = *(const short8*)&Al[(wr * 64 + fi * 16 + c) * 32 + g * 8];
#pragma unroll
    for (int fj = 0; fj < 4; ++fj)
      wf[fj] = *(const short8*)&Bl[(wc * 64 + fj * 16 + c) * 32 + g * 8];
#pragma unroll
    for (int fi = 0; fi < 4; ++fi)
#pragma unroll
      for (int fj = 0; fj < 4; ++fj)
        acc[fi][fj] = __builtin_amdgcn_mfma_f32_16x16x32_bf16(af[fi], wf[fj], acc[fi][fj], 0, 0, 0);
    __syncthreads();
  }

#pragma unroll
  for (int fi = 0; fi < 4; ++fi)
#pragma unroll
    for (int fj = 0; fj < 4; ++fj)
#pragma unroll
      for (int r = 0; r < 4; ++r) {
        int row = m0 + wr * 64 + fi * 16 + g * 4 + r;   // C row = (lane>>4)*4+reg
        int col = n0 + wc * 64 + fj * 16 + c;           // C col = lane&15
        float v = acc[fi][fj][r];
        if constexpr (ROPE) {
          float other = __shfl_xor(v, 1);
          int pi = (col & (HDc - 1)) >> 1;
          int sp = row & (Sc - 1);
          float cv = ct[sp * 64 + pi], sv = st[sp * 64 + pi];
          v = ((col & 1) == 0) ? (v * cv - other * sv) : (other * sv + v * cv);
        }
        if constexpr (RESHAPE) {
          int b_ = row >> 11, sq = row & (Sc - 1);
          int h_ = col >> 7, dd = col & (HDc - 1);
          outb[((size_t)(b_ * Hc + h_) * Sc + sq) * HDc + dd] = f2bf(v);
        } else {
          outf[(size_t)row * Dc + col] = v;
        }
      }
}

// Flash causal attention. Block = 4 waves; Q-tile 64 (16 rows/wave), KV-tile 64.
// Q in regs; K in LDS [64][136] (pad breaks stride-256B conflict); V transposed
// [128][72]; P via per-wave padded LDS [16][72].
__global__ __launch_bounds__(256) void attn_kernel(
    const short* __restrict__ qb, const short* __restrict__ kb,
    const short* __restrict__ vb, short* __restrict__ ob) {
  __shared__ short Kl[64 * 136];
  __shared__ short Vt[128 * 72];
  __shared__ short Pl[4 * 16 * 72];

  const int tid = threadIdx.x, lane = tid & 63, w = tid >> 6;
  const int g = lane >> 4, c = lane & 15;
  const int qt = blockIdx.x, bh = blockIdx.y;
  const int q0 = qt * 64;
  const short* qh = qb + (size_t)bh * Sc * HDc;
  const short* kh = kb + (size_t)bh * Sc * HDc;
  const short* vh = vb + (size_t)bh * Sc * HDc;

  short8 qf[4];
#pragma unroll
  for (int kc = 0; kc < 4; ++kc)
    qf[kc] = *(const short8*)&qh[(size_t)(q0 + w * 16 + c) * HDc + kc * 32 + g * 8];

  float mrow[4], lrow[4];
  f32x4 acc[8] = {};
#pragma unroll
  for (int r = 0; r < 4; ++r) { mrow[r] = -1e30f; lrow[r] = 0.f; }

  const int ntile = qt + 1;
  for (int kvt = 0; kvt < ntile; ++kvt) {
    const int kv0 = kvt * 64;
    // stage K [64][128] -> Kl padded
#pragma unroll
    for (int it = 0; it < 4; ++it) {
      int idx = it * 256 + tid;
      int row = idx >> 4, c8 = idx & 15;
      short8 t = *(const short8*)&kh[(size_t)(kv0 + row) * HDc + c8 * 8];
      *(short8*)&Kl[row * 136 + c8 * 8] = t;
    }
    // stage V transposed: Vt[d][kv]
#pragma unroll
    for (int it = 0; it < 4; ++it) {
      int idx = it * 256 + tid;
      int kvr = idx >> 4, c8 = idx & 15;
      short8 t = *(const short8*)&vh[(size_t)(kv0 + kvr) * HDc + c8 * 8];
#pragma unroll
      for (int j = 0; j < 8; ++j) Vt[(c8 * 8 + j) * 72 + kvr] = t[j];
    }
    __syncthreads();

    // S = Q K^T (per wave: 16 q-rows x 64 kv)
    f32x4 sacc[4];
#pragma unroll
    for (int kb_ = 0; kb_ < 4; ++kb_) {
      sacc[kb_] = (f32x4){0.f, 0.f, 0.f, 0.f};
#pragma unroll
      for (int kc = 0; kc < 4; ++kc) {
        short8 kf = *(const short8*)&Kl[(kb_ * 16 + c) * 136 + kc * 32 + g * 8];
        sacc[kb_] = __builtin_amdgcn_mfma_f32_16x16x32_bf16(qf[kc], kf, sacc[kb_], 0, 0, 0);
      }
    }
    float p[4][4];
    const bool last = (kvt == qt);
#pragma unroll
    for (int kb_ = 0; kb_ < 4; ++kb_)
#pragma unroll
      for (int r = 0; r < 4; ++r) {
        float s = sacc[kb_][r] * ATTN_SCALE;
        if (last) {
          int qg = q0 + w * 16 + g * 4 + r;
          int kg = kv0 + kb_ * 16 + c;
          if (kg > qg) s = -1e30f;
        }
        p[kb_][r] = s;
      }
    // online softmax (row r lives at lanes with same g; reduce across c)
    float scal[4], rs[4];
#pragma unroll
    for (int r = 0; r < 4; ++r) {
      float v = fmaxf(fmaxf(p[0][r], p[1][r]), fmaxf(p[2][r], p[3][r]));
      v = fmaxf(v, __shfl_xor(v, 1));
      v = fmaxf(v, __shfl_xor(v, 2));
      v = fmaxf(v, __shfl_xor(v, 4));
      v = fmaxf(v, __shfl_xor(v, 8));
      float mn = fmaxf(mrow[r], v);
      scal[r] = __expf(mrow[r] - mn);
      mrow[r] = mn;
    }
#pragma unroll
    for (int r = 0; r < 4; ++r) {
      float acc_s = 0.f;
#pragma unroll
      for (int kb_ = 0; kb_ < 4; ++kb_) {
        p[kb_][r] = __expf(p[kb_][r] - mrow[r]);
        acc_s += p[kb_][r];
      }
      acc_s += __shfl_xor(acc_s, 1);
      acc_s += __shfl_xor(acc_s, 2);
      acc_s += __shfl_xor(acc_s, 4);
      acc_s += __shfl_xor(acc_s, 8);
      rs[r] = acc_s;
      lrow[r] = lrow[r] * scal[r] + rs[r];
    }
#pragma unroll
    for (int db = 0; db < 8; ++db)
#pragma unroll
      for (int r = 0; r < 4; ++r) acc[db][r] *= scal[r];
    // P -> LDS (bf16), then read as A-frag
#pragma unroll
    for (int kb_ = 0; kb_ < 4; ++kb_)
#pragma unroll
      for (int r = 0; r < 4; ++r)
        Pl[w * 16 * 72 + (g * 4 + r) * 72 + kb_ * 16 + c] = f2bf(p[kb_][r]);
    short8 pa[2];
#pragma unroll
    for (int k2 = 0; k2 < 2; ++k2)
      pa[k2] = *(const short8*)&Pl[w * 16 * 72 + c * 72 + k2 * 32 + g * 8];
#pragma unroll
    for (int db = 0; db < 8; ++db)
#pragma unroll
      for (int k2 = 0; k2 < 2; ++k2) {
        short8 vf = *(const short8*)&Vt[(db * 16 + c) * 72 + k2 * 32 + g * 8];
        acc[db] = __builtin_amdgcn_mfma_f32_16x16x32_bf16(pa[k2], vf, acc[db], 0, 0, 0);
      }
    __syncthreads();
  }

  const int b_ = bh >> 4, h_ = bh & 15;
#pragma unroll
  for (int db = 0; db < 8; ++db)
#pragma unroll
    for (int r = 0; r < 4; ++r) {
      int qg = q0 + w * 16 + g * 4 + r;
      int d = db * 16 + c;
      float v = acc[db][r] / lrow[r];
      ob[((size_t)(b_ * Sc + qg)) * Dc + h_ * HDc + d] = f2bf(v);
    }
}

extern "C" void kernel_launch(void* const* d_in, const int* in_sizes, int n_in,
                              void* d_out, int out_size, void* d_ws, size_t ws_size,
                              hipStream_t stream) {
  const float* x = (const float*)d_in[0];
  const float* wq = (const float*)d_in[1];
  const float* wk = (const float*)d_in[2];
  const float* wv = (const float*)d_in[3];
  const float* wo = (const float*)d_in[4];
  float* out = (float*)d_out;

  char* ws = (char*)d_ws;
  short* xb  = (short*)(ws + 0);              // [4096][2048] bf16 (reused as attn-out)
  short* wqb = (short*)(ws + 16777216);
  short* wkb = (short*)(ws + 25165824);
  short* wvb = (short*)(ws + 33554432);
  short* wob = (short*)(ws + 41943040);
  short* qb  = (short*)(ws + 50331648);       // [B,H,S,HD]
  short* kbf = (short*)(ws + 67108864);
  short* vbf = (short*)(ws + 83886080);
  float* ct  = (float*)(ws + 100663296);      // [S][64]
  float* st  = (float*)(ws + 101187584);
  short* obuf = xb;                           // reuse x buffer for attention output

  cast_f32_bf16<<<Mc * Dc / 8 / 256, 256, 0, stream>>>(x, xb, Mc * Dc / 8);
  cast_f32_bf16<<<Dc * Dc / 8 / 256, 256, 0, stream>>>(wq, wqb, Dc * Dc / 8);
  cast_f32_bf16<<<Dc * Dc / 8 / 256, 256, 0, stream>>>(wk, wkb, Dc * Dc / 8);
  cast_f32_bf16<<<Dc * Dc / 8 / 256, 256, 0, stream>>>(wv, wvb, Dc * Dc / 8);
  cast_f32_bf16<<<Dc * Dc / 8 / 256, 256, 0, stream>>>(wo, wob, Dc * Dc / 8);
  rope_table<<<Sc * 64 / 256, 256, 0, stream>>>(ct, st);

  dim3 gg(Dc / 128, Mc / 128);  // (16, 32)
  gemm_nt<1, 1><<<gg, 256, 0, stream>>>(xb, wqb, qb, nullptr, ct, st);
  gemm_nt<1, 1><<<gg, 256, 0, stream>>>(xb, wkb, kbf, nullptr, ct, st);
  gemm_nt<0, 1><<<gg, 256, 0, stream>>>(xb, wvb, vbf, nullptr, ct, st);

  attn_kernel<<<dim3(Sc / 64, Bc * Hc), 256, 0, stream>>>(qb, kbf, vbf, obuf);

  gemm_nt<0, 0><<<gg, 256, 0, stream>>>(obuf, wob, nullptr, out, ct, st);
}

// Round 3
// 433.587 us; speedup vs baseline: 1.8691x; 1.8691x over previous
//
#include <hip/hip_runtime.h>
#include <stdint.h>

typedef __attribute__((ext_vector_type(4))) float f32x4;
typedef __attribute__((ext_vector_type(8))) short short8;
typedef __attribute__((ext_vector_type(4))) short s16x4;

#define DEV __device__ __forceinline__

constexpr int Bc = 2, Sc = 2048, Dc = 2048, Hc = 16, HDc = 128;
constexpr int Mc = Bc * Sc;                        // 4096 rows
constexpr float ATTN_SCALE = 0.08838834764831843f; // 1/sqrt(128)

DEV short f2bf(float f) {                          // f32 -> bf16 (RNE)
  unsigned u = __float_as_uint(f);
  unsigned r = (u + 0x7fffu + ((u >> 16) & 1u)) >> 16;
  return (short)(unsigned short)r;
}

// global -> LDS direct copy, 16B per lane. LDS dest is wave-uniform base;
// HW adds lane*16. Global source may be per-lane (enables swizzled layouts).
DEV void gload_lds16(const void* gsrc, void* ldst) {
  typedef const __attribute__((address_space(1))) void as1_cvoid;
  typedef __attribute__((address_space(3))) void as3_void;
  __builtin_amdgcn_global_load_lds((as1_cvoid*)(uintptr_t)gsrc,
                                   (as3_void*)(uint32_t)(uintptr_t)ldst,
                                   16, 0, 0);
}

__global__ void cast_f32_bf16(const float* __restrict__ in, short* __restrict__ out, int n8) {
  int i = blockIdx.x * 256 + threadIdx.x;
  if (i >= n8) return;
  f32x4 a = ((const f32x4*)in)[i * 2];
  f32x4 b = ((const f32x4*)in)[i * 2 + 1];
  short8 o;
  o[0] = f2bf(a[0]); o[1] = f2bf(a[1]); o[2] = f2bf(a[2]); o[3] = f2bf(a[3]);
  o[4] = f2bf(b[0]); o[5] = f2bf(b[1]); o[6] = f2bf(b[2]); o[7] = f2bf(b[3]);
  ((short8*)out)[i] = o;
}

__global__ void rope_table(float* __restrict__ ct, float* __restrict__ st) {
  int t = blockIdx.x * 256 + threadIdx.x;   // [0, S*64)
  int s = t >> 6, i = t & 63;
  float freq = powf(10000.0f, -(float)(2 * i) * (1.0f / 128.0f));
  float a = (float)s * freq;
  float sv, cv;
  sincosf(a, &sv, &cv);
  ct[t] = cv; st[t] = sv;
}

// ---------------------------------------------------------------------------
// Fused QKV NT-GEMM: C = x · W^T for W in {wq,wk,wv} selected by blockIdx.x.
// q,k: RoPE + reshape-store to [B,H,S,HD] bf16. v: TRANSPOSED store [B,H,HD,S].
// ---------------------------------------------------------------------------
__global__ __launch_bounds__(256) void gemm_qkv(
    const short* __restrict__ A,
    const short* __restrict__ Wq, const short* __restrict__ Wk, const short* __restrict__ Wv,
    short* __restrict__ qo, short* __restrict__ ko, short* __restrict__ vo,
    const float* __restrict__ ct, const float* __restrict__ st) {
  constexpr int K = Dc;
  __shared__ short Al[128 * 32];
  __shared__ short Bl[128 * 32];
  const int tid = threadIdx.x, lane = tid & 63, w = tid >> 6;
  const int g = lane >> 4, c = lane & 15;
  const int wr = w >> 1, wc = w & 1;
  const int m0 = blockIdx.y * 128;
  const int n0 = blockIdx.x * 128;              // 0..6143
  const int which = n0 >> 11;                   // 0=q 1=k 2=v
  const int wn0 = n0 & (Dc - 1);
  const short* W = (which == 0) ? Wq : (which == 1) ? Wk : Wv;

  f32x4 acc[4][4] = {};

  const int cid = w * 64 + lane;                // 16B chunk id within [128][32] tile
  const short* a0 = A + (size_t)(m0 + (cid >> 2)) * K + (cid & 3) * 8;
  const short* a1 = A + (size_t)(m0 + 64 + (cid >> 2)) * K + (cid & 3) * 8;
  const short* b0 = W + (size_t)(wn0 + (cid >> 2)) * K + (cid & 3) * 8;
  const short* b1 = W + (size_t)(wn0 + 64 + (cid >> 2)) * K + (cid & 3) * 8;
  char* lA0 = (char*)Al + w * 1024;
  char* lA1 = (char*)Al + 4096 + w * 1024;
  char* lB0 = (char*)Bl + w * 1024;
  char* lB1 = (char*)Bl + 4096 + w * 1024;

  for (int kt = 0; kt < K / 32; ++kt) {
    const int ko_ = kt * 32;
    gload_lds16(a0 + ko_, lA0);
    gload_lds16(a1 + ko_, lA1);
    gload_lds16(b0 + ko_, lB0);
    gload_lds16(b1 + ko_, lB1);
    __syncthreads();
    short8 af[4], wf[4];
#pragma unroll
    for (int fi = 0; fi < 4; ++fi)
      af[fi] = *(const short8*)&Al[(wr * 64 + fi * 16 + c) * 32 + g * 8];
#pragma unroll
    for (int fj = 0; fj < 4; ++fj)
      wf[fj] = *(const short8*)&Bl[(wc * 64 + fj * 16 + c) * 32 + g * 8];
#pragma unroll
    for (int fi = 0; fi < 4; ++fi)
#pragma unroll
      for (int fj = 0; fj < 4; ++fj)
        acc[fi][fj] = __builtin_amdgcn_mfma_f32_16x16x32_bf16(af[fi], wf[fj], acc[fi][fj], 0, 0, 0);
    __syncthreads();
  }

  if (which < 2) {
    short* outb = (which == 0) ? qo : ko;
#pragma unroll
    for (int fi = 0; fi < 4; ++fi)
#pragma unroll
      for (int fj = 0; fj < 4; ++fj)
#pragma unroll
        for (int r = 0; r < 4; ++r) {
          int row = m0 + wr * 64 + fi * 16 + g * 4 + r;   // C row
          int col = wn0 + wc * 64 + fj * 16 + c;          // C col (within D)
          float v = acc[fi][fj][r];
          float other = __shfl_xor(v, 1);
          int pi = (col & (HDc - 1)) >> 1;
          int sp = row & (Sc - 1);
          float cv = ct[sp * 64 + pi], sv = st[sp * 64 + pi];
          v = ((col & 1) == 0) ? (v * cv - other * sv) : (other * sv + v * cv);
          int b_ = row >> 11, sq = row & (Sc - 1);
          int h_ = col >> 7, dd = col & (HDc - 1);
          outb[((size_t)(b_ * Hc + h_) * Sc + sq) * HDc + dd] = f2bf(v);
        }
  } else {
    // V^T store: vo[b][h][dd][s], pack 4 consecutive s per lane (8B stores)
#pragma unroll
    for (int fi = 0; fi < 4; ++fi)
#pragma unroll
      for (int fj = 0; fj < 4; ++fj) {
        int row0 = m0 + wr * 64 + fi * 16 + g * 4;        // 4 consecutive rows
        int col = wn0 + wc * 64 + fj * 16 + c;
        int b_ = row0 >> 11, sq0 = row0 & (Sc - 1);
        int h_ = col >> 7, dd = col & (HDc - 1);
        s16x4 pk;
#pragma unroll
        for (int r = 0; r < 4; ++r) pk[r] = f2bf(acc[fi][fj][r]);
        *(s16x4*)&vo[((size_t)(b_ * Hc + h_) * HDc + dd) * Sc + sq0] = pk;
      }
  }
}

// Out-projection NT-GEMM, f32 output [M][D]
__global__ __launch_bounds__(256) void gemm_out(
    const short* __restrict__ A, const short* __restrict__ W, float* __restrict__ outf) {
  constexpr int K = Dc;
  __shared__ short Al[128 * 32];
  __shared__ short Bl[128 * 32];
  const int tid = threadIdx.x, lane = tid & 63, w = tid >> 6;
  const int g = lane >> 4, c = lane & 15;
  const int wr = w >> 1, wc = w & 1;
  const int m0 = blockIdx.y * 128, n0 = blockIdx.x * 128;

  f32x4 acc[4][4] = {};
  const int cid = w * 64 + lane;
  const short* a0 = A + (size_t)(m0 + (cid >> 2)) * K + (cid & 3) * 8;
  const short* a1 = A + (size_t)(m0 + 64 + (cid >> 2)) * K + (cid & 3) * 8;
  const short* b0 = W + (size_t)(n0 + (cid >> 2)) * K + (cid & 3) * 8;
  const short* b1 = W + (size_t)(n0 + 64 + (cid >> 2)) * K + (cid & 3) * 8;
  char* lA0 = (char*)Al + w * 1024;
  char* lA1 = (char*)Al + 4096 + w * 1024;
  char* lB0 = (char*)Bl + w * 1024;
  char* lB1 = (char*)Bl + 4096 + w * 1024;

  for (int kt = 0; kt < K / 32; ++kt) {
    const int ko_ = kt * 32;
    gload_lds16(a0 + ko_, lA0);
    gload_lds16(a1 + ko_, lA1);
    gload_lds16(b0 + ko_, lB0);
    gload_lds16(b1 + ko_, lB1);
    __syncthreads();
    short8 af[4], wf[4];
#pragma unroll
    for (int fi = 0; fi < 4; ++fi)
      af[fi] = *(const short8*)&Al[(wr * 64 + fi * 16 + c) * 32 + g * 8];
#pragma unroll
    for (int fj = 0; fj < 4; ++fj)
      wf[fj] = *(const short8*)&Bl[(wc * 64 + fj * 16 + c) * 32 + g * 8];
#pragma unroll
    for (int fi = 0; fi < 4; ++fi)
#pragma unroll
      for (int fj = 0; fj < 4; ++fj)
        acc[fi][fj] = __builtin_amdgcn_mfma_f32_16x16x32_bf16(af[fi], wf[fj], acc[fi][fj], 0, 0, 0);
    __syncthreads();
  }

#pragma unroll
  for (int fi = 0; fi < 4; ++fi)
#pragma unroll
    for (int fj = 0; fj < 4; ++fj)
#pragma unroll
      for (int r = 0; r < 4; ++r) {
        int row = m0 + wr * 64 + fi * 16 + g * 4 + r;
        int col = n0 + wc * 64 + fj * 16 + c;
        outf[(size_t)row * Dc + col] = acc[fi][fj][r];
      }
}

// ---------------------------------------------------------------------------
// Flash causal attention. 4 waves; per pass: Q-tile 64 (16 rows/wave), KV 64.
// K tile [64][128] and V^T tile [128][64] staged via global_load_lds with
// XOR chunk-swizzle (chunk ^= row&7, pre-swizzled global src), 2-phase dbuf.
// Each block handles q-tiles {x, 31-x} -> uniform 33 KV-iters per block.
// ---------------------------------------------------------------------------
DEV void stage_kv(const short* kh, const short* vth, int kv0,
                  short* Kb, short* Vb, int w, int tid) {
#pragma unroll
  for (int i = 0; i < 4; ++i) {                 // K: 1024 chunks, 16/row
    int L = i * 256 + tid;
    int row = L >> 4, p = L & 15;
    gload_lds16(kh + (size_t)(kv0 + row) * HDc + ((p ^ (row & 7)) * 8),
                (char*)Kb + i * 4096 + w * 1024);
  }
#pragma unroll
  for (int i = 0; i < 4; ++i) {                 // V^T: 1024 chunks, 8/row
    int L = i * 256 + tid;
    int row = L >> 3, p = L & 7;
    gload_lds16(vth + (size_t)row * Sc + kv0 + ((p ^ (row & 7)) * 8),
                (char*)Vb + i * 4096 + w * 1024);
  }
}

__global__ __launch_bounds__(256) void attn_kernel(
    const short* __restrict__ qb, const short* __restrict__ kb,
    const short* __restrict__ vtb, short* __restrict__ ob) {
  __shared__ short Kl[2][64 * 128];
  __shared__ short Vl[2][128 * 64];
  __shared__ short Pl[4 * 16 * 72];

  const int tid = threadIdx.x, lane = tid & 63, w = tid >> 6;
  const int g = lane >> 4, c = lane & 15;
  const int bh = blockIdx.y;
  const int b_ = bh >> 4, h_ = bh & 15;
  const short* qh = qb + (size_t)bh * Sc * HDc;
  const short* kh = kb + (size_t)bh * Sc * HDc;
  const short* vth = vtb + (size_t)bh * HDc * Sc;

  for (int pass = 0; pass < 2; ++pass) {
    const int qt = pass ? (31 - blockIdx.x) : blockIdx.x;
    const int q0 = qt * 64;

    short8 qf[4];
#pragma unroll
    for (int kc = 0; kc < 4; ++kc)
      qf[kc] = *(const short8*)&qh[(size_t)(q0 + w * 16 + c) * HDc + kc * 32 + g * 8];

    float mrow[4], lrow[4];
    f32x4 acc[8] = {};
#pragma unroll
    for (int r = 0; r < 4; ++r) { mrow[r] = -1e30f; lrow[r] = 0.f; }

    const int nt = qt + 1;
    int cur = 0;
    stage_kv(kh, vth, 0, Kl[0], Vl[0], w, tid);
    __syncthreads();

    for (int kvt = 0; kvt < nt; ++kvt) {
      if (kvt + 1 < nt)
        stage_kv(kh, vth, (kvt + 1) * 64, Kl[cur ^ 1], Vl[cur ^ 1], w, tid);

      // S = Q K^T (wave: 16 q-rows x 64 kv)
      f32x4 sacc[4];
#pragma unroll
      for (int kb_ = 0; kb_ < 4; ++kb_) {
        sacc[kb_] = (f32x4){0.f, 0.f, 0.f, 0.f};
#pragma unroll
        for (int kc = 0; kc < 4; ++kc) {
          short8 kf = *(const short8*)&Kl[cur][(kb_ * 16 + c) * 128 + (((kc * 4 + g) ^ (c & 7)) * 8)];
          sacc[kb_] = __builtin_amdgcn_mfma_f32_16x16x32_bf16(qf[kc], kf, sacc[kb_], 0, 0, 0);
        }
      }
      float p[4][4];
      const bool last = (kvt == qt);
      const int kv0 = kvt * 64;
#pragma unroll
      for (int kb_ = 0; kb_ < 4; ++kb_)
#pragma unroll
        for (int r = 0; r < 4; ++r) {
          float s = sacc[kb_][r] * ATTN_SCALE;
          if (last) {
            int qg = q0 + w * 16 + g * 4 + r;
            int kg = kv0 + kb_ * 16 + c;
            if (kg > qg) s = -1e30f;
          }
          p[kb_][r] = s;
        }
      // online softmax (row r at lanes sharing g; reduce across c)
      float scal[4];
#pragma unroll
      for (int r = 0; r < 4; ++r) {
        float v = fmaxf(fmaxf(p[0][r], p[1][r]), fmaxf(p[2][r], p[3][r]));
        v = fmaxf(v, __shfl_xor(v, 1));
        v = fmaxf(v, __shfl_xor(v, 2));
        v = fmaxf(v, __shfl_xor(v, 4));
        v = fmaxf(v, __shfl_xor(v, 8));
        float mn = fmaxf(mrow[r], v);
        scal[r] = __expf(mrow[r] - mn);
        mrow[r] = mn;
      }
#pragma unroll
      for (int r = 0; r < 4; ++r) {
        float acc_s = 0.f;
#pragma unroll
        for (int kb_ = 0; kb_ < 4; ++kb_) {
          p[kb_][r] = __expf(p[kb_][r] - mrow[r]);
          acc_s += p[kb_][r];
        }
        acc_s += __shfl_xor(acc_s, 1);
        acc_s += __shfl_xor(acc_s, 2);
        acc_s += __shfl_xor(acc_s, 4);
        acc_s += __shfl_xor(acc_s, 8);
        lrow[r] = lrow[r] * scal[r] + acc_s;
      }
#pragma unroll
      for (int db = 0; db < 8; ++db)
#pragma unroll
        for (int r = 0; r < 4; ++r) acc[db][r] *= scal[r];
      // P -> per-wave LDS (bf16), read back as A-frag
#pragma unroll
      for (int kb_ = 0; kb_ < 4; ++kb_)
#pragma unroll
        for (int r = 0; r < 4; ++r)
          Pl[w * 16 * 72 + (g * 4 + r) * 72 + kb_ * 16 + c] = f2bf(p[kb_][r]);
      short8 pa[2];
#pragma unroll
      for (int k2 = 0; k2 < 2; ++k2)
        pa[k2] = *(const short8*)&Pl[w * 16 * 72 + c * 72 + k2 * 32 + g * 8];
#pragma unroll
      for (int db = 0; db < 8; ++db)
#pragma unroll
        for (int k2 = 0; k2 < 2; ++k2) {
          short8 vf = *(const short8*)&Vl[cur][(db * 16 + c) * 64 + (((k2 * 4 + g) ^ (c & 7)) * 8)];
          acc[db] = __builtin_amdgcn_mfma_f32_16x16x32_bf16(pa[k2], vf, acc[db], 0, 0, 0);
        }
      __syncthreads();
      cur ^= 1;
    }

#pragma unroll
    for (int db = 0; db < 8; ++db)
#pragma unroll
      for (int r = 0; r < 4; ++r) {
        int qg = q0 + w * 16 + g * 4 + r;
        int d = db * 16 + c;
        float v = acc[db][r] / lrow[r];
        ob[((size_t)(b_ * Sc + qg)) * Dc + h_ * HDc + d] = f2bf(v);
      }
  }
}

extern "C" void kernel_launch(void* const* d_in, const int* in_sizes, int n_in,
                              void* d_out, int out_size, void* d_ws, size_t ws_size,
                              hipStream_t stream) {
  const float* x = (const float*)d_in[0];
  const float* wq = (const float*)d_in[1];
  const float* wk = (const float*)d_in[2];
  const float* wv = (const float*)d_in[3];
  const float* wo = (const float*)d_in[4];
  float* out = (float*)d_out;

  char* ws = (char*)d_ws;
  short* xb  = (short*)(ws + 0);              // [4096][2048] bf16 (reused as attn-out)
  short* wqb = (short*)(ws + 16777216);
  short* wkb = (short*)(ws + 25165824);
  short* wvb = (short*)(ws + 33554432);
  short* wob = (short*)(ws + 41943040);
  short* qb  = (short*)(ws + 50331648);       // [B,H,S,HD]
  short* kbf = (short*)(ws + 67108864);       // [B,H,S,HD]
  short* vtb = (short*)(ws + 83886080);       // [B,H,HD,S]  (transposed V)
  float* ct  = (float*)(ws + 100663296);      // [S][64]
  float* st  = (float*)(ws + 101187584);
  short* obuf = xb;                           // reuse x buffer for attention output

  cast_f32_bf16<<<Mc * Dc / 8 / 256, 256, 0, stream>>>(x, xb, Mc * Dc / 8);
  cast_f32_bf16<<<Dc * Dc / 8 / 256, 256, 0, stream>>>(wq, wqb, Dc * Dc / 8);
  cast_f32_bf16<<<Dc * Dc / 8 / 256, 256, 0, stream>>>(wk, wkb, Dc * Dc / 8);
  cast_f32_bf16<<<Dc * Dc / 8 / 256, 256, 0, stream>>>(wv, wvb, Dc * Dc / 8);
  cast_f32_bf16<<<Dc * Dc / 8 / 256, 256, 0, stream>>>(wo, wob, Dc * Dc / 8);
  rope_table<<<Sc * 64 / 256, 256, 0, stream>>>(ct, st);

  gemm_qkv<<<dim3(3 * Dc / 128, Mc / 128), 256, 0, stream>>>(xb, wqb, wkb, wvb, qb, kbf, vtb, ct, st);

  attn_kernel<<<dim3(Sc / 128, Bc * Hc), 256, 0, stream>>>(qb, kbf, vtb, obuf);

  gemm_out<<<dim3(Dc / 128, Mc / 128), 256, 0, stream>>>(obuf, wob, out);
}

// Round 4
// 397.091 us; speedup vs baseline: 2.0409x; 1.0919x over previous
//
#include <hip/hip_runtime.h>
#include <stdint.h>

typedef __attribute__((ext_vector_type(4))) float f32x4;
typedef __attribute__((ext_vector_type(8))) short short8;
typedef __attribute__((ext_vector_type(4))) short s16x4;

#define DEV __device__ __forceinline__

constexpr int Bc = 2, Sc = 2048, Dc = 2048, Hc = 16, HDc = 128;
constexpr int Mc = Bc * Sc;                        // 4096 rows
constexpr float ATTN_SCALE = 0.08838834764831843f; // 1/sqrt(128)

DEV short f2bf(float f) {                          // f32 -> bf16 (RNE)
  unsigned u = __float_as_uint(f);
  unsigned r = (u + 0x7fffu + ((u >> 16) & 1u)) >> 16;
  return (short)(unsigned short)r;
}

// global -> LDS direct copy, 16B per lane. LDS dest is wave-uniform base;
// HW adds lane*16. Global source may be per-lane (enables swizzled layouts).
DEV void gload_lds16(const void* gsrc, void* ldst) {
  typedef const __attribute__((address_space(1))) void as1_cvoid;
  typedef __attribute__((address_space(3))) void as3_void;
  __builtin_amdgcn_global_load_lds((as1_cvoid*)(uintptr_t)gsrc,
                                   (as3_void*)(uint32_t)(uintptr_t)ldst,
                                   16, 0, 0);
}

__global__ void cast_f32_bf16(const float* __restrict__ in, short* __restrict__ out, int n8) {
  int i = blockIdx.x * 256 + threadIdx.x;
  if (i >= n8) return;
  f32x4 a = ((const f32x4*)in)[i * 2];
  f32x4 b = ((const f32x4*)in)[i * 2 + 1];
  short8 o;
  o[0] = f2bf(a[0]); o[1] = f2bf(a[1]); o[2] = f2bf(a[2]); o[3] = f2bf(a[3]);
  o[4] = f2bf(b[0]); o[5] = f2bf(b[1]); o[6] = f2bf(b[2]); o[7] = f2bf(b[3]);
  ((short8*)out)[i] = o;
}

__global__ void rope_table(float* __restrict__ ct, float* __restrict__ st) {
  int t = blockIdx.x * 256 + threadIdx.x;   // [0, S*64)
  int s = t >> 6, i = t & 63;
  float freq = powf(10000.0f, -(float)(2 * i) * (1.0f / 128.0f));
  float a = (float)s * freq;
  float sv, cv;
  sincosf(a, &sv, &cv);
  ct[t] = cv; st[t] = sv;
}

// ---------------------------------------------------------------------------
// Deep-pipelined NT-GEMM: BM=128, BN=256, BK=64, 512 thr (8 waves, 2M x 4N).
// Double-buffered LDS, counted vmcnt(6), T2 chunk-XOR swizzle, T5 setprio.
// EPI=0: fused QKV (RoPE+reshape for q,k; transposed store for v).
// EPI=1: out-projection, f32 row-major store.
// ---------------------------------------------------------------------------
template <int EPI>
__global__ __launch_bounds__(512, 2) void gemm_pipe(
    const short* __restrict__ A,
    const short* __restrict__ W0, const short* __restrict__ W1, const short* __restrict__ W2,
    short* __restrict__ qo, short* __restrict__ ko, short* __restrict__ vo,
    float* __restrict__ outf,
    const float* __restrict__ ct, const float* __restrict__ st) {
  constexpr int K = Dc, NT = K / 64;
  __shared__ short As[2][128][64];       // 32 KB
  __shared__ short Bs[2][2][128][64];    // 64 KB

  const int tid = threadIdx.x, lane = tid & 63, w = tid >> 6;
  const int g = lane >> 4, c = lane & 15;
  const int wr = w >> 2, wc = w & 3;

  // bijective XCD swizzle (nwg % 8 == 0)
  const int nx = gridDim.x;
  const int nwg = nx * gridDim.y;
  const int flat = blockIdx.y * nx + blockIdx.x;
  const int swz = (flat & 7) * (nwg >> 3) + (flat >> 3);
  const int nbx = swz % nx, nby = swz / nx;

  const int m0 = nby * 128;
  const int which = (EPI == 0) ? (nbx >> 3) : 0;   // 0=q 1=k 2=v
  const int wn0 = (EPI == 0) ? ((nbx & 7) * 256) : (nbx * 256);
  const short* W = (EPI == 1) ? W0 : ((which == 0) ? W0 : (which == 1) ? W1 : W2);

  // staging addresses: thread -> rows r1(+64/128/192), chunk p1, swizzled
  const int r1 = tid >> 3, p1 = tid & 7;
  const int psw = (p1 ^ (r1 & 7)) * 8;             // element offset within row
  const short* gA0 = A + (size_t)(m0 + r1) * K + psw;
  const short* gA1 = gA0 + (size_t)64 * K;
  const short* gB0 = W + (size_t)(wn0 + r1) * K + psw;
  const short* gB1 = gB0 + (size_t)64 * K;
  const short* gB2 = gB0 + (size_t)128 * K;
  const short* gB3 = gB0 + (size_t)192 * K;
  char* ldsA = (char*)As + w * 1024;
  char* ldsB = (char*)Bs + w * 1024;

#define STAGE(t, db)                                        \
  do {                                                      \
    const size_t ko_ = (size_t)(t) * 64;                    \
    gload_lds16(gA0 + ko_, ldsA + (db) * 16384);            \
    gload_lds16(gA1 + ko_, ldsA + (db) * 16384 + 8192);     \
    gload_lds16(gB0 + ko_, ldsB + (db) * 32768);            \
    gload_lds16(gB1 + ko_, ldsB + (db) * 32768 + 8192);     \
    gload_lds16(gB2 + ko_, ldsB + (db) * 32768 + 16384);    \
    gload_lds16(gB3 + ko_, ldsB + (db) * 32768 + 24576);    \
  } while (0)

  f32x4 acc[4][4] = {};
  const int cx = (g ^ (c & 7)) * 16;               // swizzled chunk byte (kk=0)
  const char* aBase = (const char*)As + (wr * 64 + c) * 128;
  const char* bBase = (const char*)Bs + (wc >> 1) * 16384 + ((wc & 1) * 64 + c) * 128;

  STAGE(0, 0);
  STAGE(1, 1);
  asm volatile("s_waitcnt vmcnt(6)" ::: "memory");
  __builtin_amdgcn_sched_barrier(0);
  __builtin_amdgcn_s_barrier();

  for (int t = 0; t < NT; ++t) {
    const int db = t & 1;
    short8 af[2][4], bf[2][4];
    const char* aB = aBase + db * 16384;
    const char* bB = bBase + db * 32768;
#pragma unroll
    for (int kk = 0; kk < 2; ++kk) {
      const int co = cx ^ (kk * 64);
#pragma unroll
      for (int mi = 0; mi < 4; ++mi) af[kk][mi] = *(const short8*)(aB + mi * 2048 + co);
#pragma unroll
      for (int nj = 0; nj < 4; ++nj) bf[kk][nj] = *(const short8*)(bB + nj * 2048 + co);
    }
    asm volatile("s_waitcnt lgkmcnt(0)" ::: "memory");
    __builtin_amdgcn_sched_barrier(0);
    __builtin_amdgcn_s_barrier();        // all waves done reading buf[db]
    __builtin_amdgcn_sched_barrier(0);
    if (t + 2 < NT) STAGE(t + 2, db);    // safe: buf[db] fully consumed
    __builtin_amdgcn_s_setprio(1);
#pragma unroll
    for (int kk = 0; kk < 2; ++kk)
#pragma unroll
      for (int mi = 0; mi < 4; ++mi)
#pragma unroll
        for (int nj = 0; nj < 4; ++nj)
          acc[mi][nj] = __builtin_amdgcn_mfma_f32_16x16x32_bf16(af[kk][mi], bf[kk][nj], acc[mi][nj], 0, 0, 0);
    __builtin_amdgcn_s_setprio(0);
    if (t + 2 < NT) { asm volatile("s_waitcnt vmcnt(6)" ::: "memory"); }
    else            { asm volatile("s_waitcnt vmcnt(0)" ::: "memory"); }
    __builtin_amdgcn_sched_barrier(0);
    __builtin_amdgcn_s_barrier();        // tile t+1 fully visible
  }
#undef STAGE

  if constexpr (EPI == 0) {
    if (which < 2) {
      short* outb = (which == 0) ? qo : ko;
#pragma unroll
      for (int mi = 0; mi < 4; ++mi)
#pragma unroll
        for (int nj = 0; nj < 4; ++nj)
#pragma unroll
          for (int r = 0; r < 4; ++r) {
            int row = m0 + wr * 64 + mi * 16 + g * 4 + r;
            int col = wn0 + wc * 64 + nj * 16 + c;
            float v = acc[mi][nj][r];
            float other = __shfl_xor(v, 1);
            int pi = (col & (HDc - 1)) >> 1;
            int sp = row & (Sc - 1);
            float cv = ct[sp * 64 + pi], sv = st[sp * 64 + pi];
            v = ((col & 1) == 0) ? (v * cv - other * sv) : (other * sv + v * cv);
            int b_ = row >> 11, sq = row & (Sc - 1);
            int h_ = col >> 7, dd = col & (HDc - 1);
            outb[((size_t)(b_ * Hc + h_) * Sc + sq) * HDc + dd] = f2bf(v);
          }
    } else {
      // V^T store: vo[b][h][dd][s]
#pragma unroll
      for (int mi = 0; mi < 4; ++mi)
#pragma unroll
        for (int nj = 0; nj < 4; ++nj) {
          int row0 = m0 + wr * 64 + mi * 16 + g * 4;
          int col = wn0 + wc * 64 + nj * 16 + c;
          int b_ = row0 >> 11, sq0 = row0 & (Sc - 1);
          int h_ = col >> 7, dd = col & (HDc - 1);
          s16x4 pk;
#pragma unroll
          for (int r = 0; r < 4; ++r) pk[r] = f2bf(acc[mi][nj][r]);
          *(s16x4*)&vo[((size_t)(b_ * Hc + h_) * HDc + dd) * Sc + sq0] = pk;
        }
    }
  } else {
#pragma unroll
    for (int mi = 0; mi < 4; ++mi)
#pragma unroll
      for (int nj = 0; nj < 4; ++nj)
#pragma unroll
        for (int r = 0; r < 4; ++r) {
          int row = m0 + wr * 64 + mi * 16 + g * 4 + r;
          int col = wn0 + wc * 64 + nj * 16 + c;
          outf[(size_t)row * Dc + col] = acc[mi][nj][r];
        }
  }
}

// ---------------------------------------------------------------------------
// Flash causal attention. 4 waves; per pass: Q-tile 64 (16 rows/wave), KV 64.
// K tile [64][128] and V^T tile [128][64] staged via global_load_lds with
// XOR chunk-swizzle (chunk ^= row&7, pre-swizzled global src), 2-phase dbuf.
// Each block handles q-tiles {x, 31-x} -> uniform 33 KV-iters per block.
// ---------------------------------------------------------------------------
DEV void stage_kv(const short* kh, const short* vth, int kv0,
                  short* Kb, short* Vb, int w, int tid) {
#pragma unroll
  for (int i = 0; i < 4; ++i) {                 // K: 1024 chunks, 16/row
    int L = i * 256 + tid;
    int row = L >> 4, p = L & 15;
    gload_lds16(kh + (size_t)(kv0 + row) * HDc + ((p ^ (row & 7)) * 8),
                (char*)Kb + i * 4096 + w * 1024);
  }
#pragma unroll
  for (int i = 0; i < 4; ++i) {                 // V^T: 1024 chunks, 8/row
    int L = i * 256 + tid;
    int row = L >> 3, p = L & 7;
    gload_lds16(vth + (size_t)row * Sc + kv0 + ((p ^ (row & 7)) * 8),
                (char*)Vb + i * 4096 + w * 1024);
  }
}

__global__ __launch_bounds__(256) void attn_kernel(
    const short* __restrict__ qb, const short* __restrict__ kb,
    const short* __restrict__ vtb, short* __restrict__ ob) {
  __shared__ short Kl[2][64 * 128];
  __shared__ short Vl[2][128 * 64];
  __shared__ short Pl[4 * 16 * 72];

  const int tid = threadIdx.x, lane = tid & 63, w = tid >> 6;
  const int g = lane >> 4, c = lane & 15;
  const int bh = blockIdx.y;
  const int b_ = bh >> 4, h_ = bh & 15;
  const short* qh = qb + (size_t)bh * Sc * HDc;
  const short* kh = kb + (size_t)bh * Sc * HDc;
  const short* vth = vtb + (size_t)bh * HDc * Sc;

  for (int pass = 0; pass < 2; ++pass) {
    const int qt = pass ? (31 - blockIdx.x) : blockIdx.x;
    const int q0 = qt * 64;

    short8 qf[4];
#pragma unroll
    for (int kc = 0; kc < 4; ++kc)
      qf[kc] = *(const short8*)&qh[(size_t)(q0 + w * 16 + c) * HDc + kc * 32 + g * 8];

    float mrow[4], lrow[4];
    f32x4 acc[8] = {};
#pragma unroll
    for (int r = 0; r < 4; ++r) { mrow[r] = -1e30f; lrow[r] = 0.f; }

    const int nt = qt + 1;
    int cur = 0;
    stage_kv(kh, vth, 0, Kl[0], Vl[0], w, tid);
    __syncthreads();

    for (int kvt = 0; kvt < nt; ++kvt) {
      if (kvt + 1 < nt)
        stage_kv(kh, vth, (kvt + 1) * 64, Kl[cur ^ 1], Vl[cur ^ 1], w, tid);

      // S = Q K^T (wave: 16 q-rows x 64 kv)
      f32x4 sacc[4];
#pragma unroll
      for (int kb_ = 0; kb_ < 4; ++kb_) {
        sacc[kb_] = (f32x4){0.f, 0.f, 0.f, 0.f};
#pragma unroll
        for (int kc = 0; kc < 4; ++kc) {
          short8 kf = *(const short8*)&Kl[cur][(kb_ * 16 + c) * 128 + (((kc * 4 + g) ^ (c & 7)) * 8)];
          sacc[kb_] = __builtin_amdgcn_mfma_f32_16x16x32_bf16(qf[kc], kf, sacc[kb_], 0, 0, 0);
        }
      }
      float p[4][4];
      const bool last = (kvt == qt);
      const int kv0 = kvt * 64;
#pragma unroll
      for (int kb_ = 0; kb_ < 4; ++kb_)
#pragma unroll
        for (int r = 0; r < 4; ++r) {
          float s = sacc[kb_][r] * ATTN_SCALE;
          if (last) {
            int qg = q0 + w * 16 + g * 4 + r;
            int kg = kv0 + kb_ * 16 + c;
            if (kg > qg) s = -1e30f;
          }
          p[kb_][r] = s;
        }
      // online softmax (row r at lanes sharing g; reduce across c)
      float scal[4];
#pragma unroll
      for (int r = 0; r < 4; ++r) {
        float v = fmaxf(fmaxf(p[0][r], p[1][r]), fmaxf(p[2][r], p[3][r]));
        v = fmaxf(v, __shfl_xor(v, 1));
        v = fmaxf(v, __shfl_xor(v, 2));
        v = fmaxf(v, __shfl_xor(v, 4));
        v = fmaxf(v, __shfl_xor(v, 8));
        float mn = fmaxf(mrow[r], v);
        scal[r] = __expf(mrow[r] - mn);
        mrow[r] = mn;
      }
#pragma unroll
      for (int r = 0; r < 4; ++r) {
        float acc_s = 0.f;
#pragma unroll
        for (int kb_ = 0; kb_ < 4; ++kb_) {
          p[kb_][r] = __expf(p[kb_][r] - mrow[r]);
          acc_s += p[kb_][r];
        }
        acc_s += __shfl_xor(acc_s, 1);
        acc_s += __shfl_xor(acc_s, 2);
        acc_s += __shfl_xor(acc_s, 4);
        acc_s += __shfl_xor(acc_s, 8);
        lrow[r] = lrow[r] * scal[r] + acc_s;
      }
#pragma unroll
      for (int db = 0; db < 8; ++db)
#pragma unroll
        for (int r = 0; r < 4; ++r) acc[db][r] *= scal[r];
      // P -> per-wave LDS (bf16), read back as A-frag
#pragma unroll
      for (int kb_ = 0; kb_ < 4; ++kb_)
#pragma unroll
        for (int r = 0; r < 4; ++r)
          Pl[w * 16 * 72 + (g * 4 + r) * 72 + kb_ * 16 + c] = f2bf(p[kb_][r]);
      short8 pa[2];
#pragma unroll
      for (int k2 = 0; k2 < 2; ++k2)
        pa[k2] = *(const short8*)&Pl[w * 16 * 72 + c * 72 + k2 * 32 + g * 8];
#pragma unroll
      for (int db = 0; db < 8; ++db)
#pragma unroll
        for (int k2 = 0; k2 < 2; ++k2) {
          short8 vf = *(const short8*)&Vl[cur][(db * 16 + c) * 64 + (((k2 * 4 + g) ^ (c & 7)) * 8)];
          acc[db] = __builtin_amdgcn_mfma_f32_16x16x32_bf16(pa[k2], vf, acc[db], 0, 0, 0);
        }
      __syncthreads();
      cur ^= 1;
    }

#pragma unroll
    for (int db = 0; db < 8; ++db)
#pragma unroll
      for (int r = 0; r < 4; ++r) {
        int qg = q0 + w * 16 + g * 4 + r;
        int d = db * 16 + c;
        float v = acc[db][r] / lrow[r];
        ob[((size_t)(b_ * Sc + qg)) * Dc + h_ * HDc + d] = f2bf(v);
      }
  }
}

extern "C" void kernel_launch(void* const* d_in, const int* in_sizes, int n_in,
                              void* d_out, int out_size, void* d_ws, size_t ws_size,
                              hipStream_t stream) {
  const float* x = (const float*)d_in[0];
  const float* wq = (const float*)d_in[1];
  const float* wk = (const float*)d_in[2];
  const float* wv = (const float*)d_in[3];
  const float* wo = (const float*)d_in[4];
  float* out = (float*)d_out;

  char* ws = (char*)d_ws;
  short* xb  = (short*)(ws + 0);              // [4096][2048] bf16 (reused as attn-out)
  short* wqb = (short*)(ws + 16777216);
  short* wkb = (short*)(ws + 25165824);
  short* wvb = (short*)(ws + 33554432);
  short* wob = (short*)(ws + 41943040);
  short* qb  = (short*)(ws + 50331648);       // [B,H,S,HD]
  short* kbf = (short*)(ws + 67108864);       // [B,H,S,HD]
  short* vtb = (short*)(ws + 83886080);       // [B,H,HD,S]  (transposed V)
  float* ct  = (float*)(ws + 100663296);      // [S][64]
  float* st  = (float*)(ws + 101187584);
  short* obuf = xb;                           // reuse x buffer for attention output

  cast_f32_bf16<<<Mc * Dc / 8 / 256, 256, 0, stream>>>(x, xb, Mc * Dc / 8);
  cast_f32_bf16<<<Dc * Dc / 8 / 256, 256, 0, stream>>>(wq, wqb, Dc * Dc / 8);
  cast_f32_bf16<<<Dc * Dc / 8 / 256, 256, 0, stream>>>(wk, wkb, Dc * Dc / 8);
  cast_f32_bf16<<<Dc * Dc / 8 / 256, 256, 0, stream>>>(wv, wvb, Dc * Dc / 8);
  cast_f32_bf16<<<Dc * Dc / 8 / 256, 256, 0, stream>>>(wo, wob, Dc * Dc / 8);
  rope_table<<<Sc * 64 / 256, 256, 0, stream>>>(ct, st);

  // QKV: N = 3*2048 over BN=256 -> 24 x-blocks; M=4096 over BM=128 -> 32 y-blocks
  gemm_pipe<0><<<dim3(24, 32), 512, 0, stream>>>(xb, wqb, wkb, wvb, qb, kbf, vtb, nullptr, ct, st);

  attn_kernel<<<dim3(Sc / 128, Bc * Hc), 256, 0, stream>>>(qb, kbf, vtb, obuf);

  // Out-proj: N = 2048 -> 8 x-blocks
  gemm_pipe<1><<<dim3(8, 32), 512, 0, stream>>>(obuf, wob, nullptr, nullptr,
                                                nullptr, nullptr, nullptr, out, ct, st);
}

// Round 5
// 392.376 us; speedup vs baseline: 2.0654x; 1.0120x over previous
//
#include <hip/hip_runtime.h>
#include <stdint.h>

typedef __attribute__((ext_vector_type(4))) float f32x4;
typedef __attribute__((ext_vector_type(8))) short short8;
typedef __attribute__((ext_vector_type(4))) short s16x4;

#define DEV __device__ __forceinline__

constexpr int Bc = 2, Sc = 2048, Dc = 2048, Hc = 16, HDc = 128;
constexpr int Mc = Bc * Sc;                        // 4096 rows
constexpr float ATTN_SCALE = 0.08838834764831843f; // 1/sqrt(128)

DEV short f2bf(float f) {                          // f32 -> bf16 (RNE)
  unsigned u = __float_as_uint(f);
  unsigned r = (u + 0x7fffu + ((u >> 16) & 1u)) >> 16;
  return (short)(unsigned short)r;
}

// global -> LDS direct copy, 16B per lane. LDS dest is wave-uniform base;
// HW adds lane*16. Global source may be per-lane (enables swizzled layouts).
DEV void gload_lds16(const void* gsrc, void* ldst) {
  typedef const __attribute__((address_space(1))) void as1_cvoid;
  typedef __attribute__((address_space(3))) void as3_void;
  __builtin_amdgcn_global_load_lds((as1_cvoid*)(uintptr_t)gsrc,
                                   (as3_void*)(uint32_t)(uintptr_t)ldst,
                                   16, 0, 0);
}

__global__ void cast_f32_bf16(const float* __restrict__ in, short* __restrict__ out, int n8) {
  int i = blockIdx.x * 256 + threadIdx.x;
  if (i >= n8) return;
  f32x4 a = ((const f32x4*)in)[i * 2];
  f32x4 b = ((const f32x4*)in)[i * 2 + 1];
  short8 o;
  o[0] = f2bf(a[0]); o[1] = f2bf(a[1]); o[2] = f2bf(a[2]); o[3] = f2bf(a[3]);
  o[4] = f2bf(b[0]); o[5] = f2bf(b[1]); o[6] = f2bf(b[2]); o[7] = f2bf(b[3]);
  ((short8*)out)[i] = o;
}

__global__ void rope_table(float* __restrict__ ct, float* __restrict__ st) {
  int t = blockIdx.x * 256 + threadIdx.x;   // [0, S*64)
  int s = t >> 6, i = t & 63;
  float freq = powf(10000.0f, -(float)(2 * i) * (1.0f / 128.0f));
  float a = (float)s * freq;
  float sv, cv;
  sincosf(a, &sv, &cv);
  ct[t] = cv; st[t] = sv;
}

// ---------------------------------------------------------------------------
// Deep-pipelined NT-GEMM: BM=128, BN=256, BK=64, 512 thr (8 waves, 2M x 4N).
// LDS double-buffer + REGISTER frag double-buffer: ds_reads for tile t+1 are
// issued before MFMA(t) so the LDS port drains under the MFMA pipe.
// Counted vmcnt(6), T2 chunk-XOR swizzle, T5 setprio, T1 XCD swizzle.
// EPI=0: fused QKV (RoPE+reshape for q,k; transposed store for v).
// EPI=1: out-projection, f32 row-major store.
// ---------------------------------------------------------------------------
template <int EPI>
__global__ __launch_bounds__(512, 2) void gemm_pipe(
    const short* __restrict__ A,
    const short* __restrict__ W0, const short* __restrict__ W1, const short* __restrict__ W2,
    short* __restrict__ qo, short* __restrict__ ko, short* __restrict__ vo,
    float* __restrict__ outf,
    const float* __restrict__ ct, const float* __restrict__ st) {
  constexpr int K = Dc, NT = K / 64;
  __shared__ short As[2][128][64];       // 32 KB
  __shared__ short Bs[2][2][128][64];    // 64 KB

  const int tid = threadIdx.x, lane = tid & 63, w = tid >> 6;
  const int g = lane >> 4, c = lane & 15;
  const int wr = w >> 2, wc = w & 3;

  // bijective XCD swizzle (nwg % 8 == 0)
  const int nx = gridDim.x;
  const int nwg = nx * gridDim.y;
  const int flat = blockIdx.y * nx + blockIdx.x;
  const int swz = (flat & 7) * (nwg >> 3) + (flat >> 3);
  const int nbx = swz % nx, nby = swz / nx;

  const int m0 = nby * 128;
  const int which = (EPI == 0) ? (nbx >> 3) : 0;   // 0=q 1=k 2=v
  const int wn0 = (EPI == 0) ? ((nbx & 7) * 256) : (nbx * 256);
  const short* W = (EPI == 1) ? W0 : ((which == 0) ? W0 : (which == 1) ? W1 : W2);

  // staging addresses: thread -> rows r1(+64/128/192), chunk p1, swizzled
  const int r1 = tid >> 3, p1 = tid & 7;
  const int psw = (p1 ^ (r1 & 7)) * 8;             // element offset within row
  const short* gA0 = A + (size_t)(m0 + r1) * K + psw;
  const short* gA1 = gA0 + (size_t)64 * K;
  const short* gB0 = W + (size_t)(wn0 + r1) * K + psw;
  const short* gB1 = gB0 + (size_t)64 * K;
  const short* gB2 = gB0 + (size_t)128 * K;
  const short* gB3 = gB0 + (size_t)192 * K;
  char* ldsA = (char*)As + w * 1024;
  char* ldsB = (char*)Bs + w * 1024;

#define STAGE(t, db)                                        \
  do {                                                      \
    const size_t ko_ = (size_t)(t) * 64;                    \
    gload_lds16(gA0 + ko_, ldsA + (db) * 16384);            \
    gload_lds16(gA1 + ko_, ldsA + (db) * 16384 + 8192);     \
    gload_lds16(gB0 + ko_, ldsB + (db) * 32768);            \
    gload_lds16(gB1 + ko_, ldsB + (db) * 32768 + 8192);     \
    gload_lds16(gB2 + ko_, ldsB + (db) * 32768 + 16384);    \
    gload_lds16(gB3 + ko_, ldsB + (db) * 32768 + 24576);    \
  } while (0)

  f32x4 acc[4][4] = {};
  const int cx = (g ^ (c & 7)) * 16;               // swizzled chunk byte (kk=0)
  const char* aBase = (const char*)As + (wr * 64 + c) * 128;
  const char* bBase = (const char*)Bs + (wc >> 1) * 16384 + ((wc & 1) * 64 + c) * 128;

  short8 afA[2][4], bfA[2][4], afB[2][4], bfB[2][4];

#define READ_FRAGS(af, bf, db)                                                        \
  do {                                                                                \
    const char* aB = aBase + (db) * 16384;                                            \
    const char* bB = bBase + (db) * 32768;                                            \
    _Pragma("unroll")                                                                 \
    for (int kk = 0; kk < 2; ++kk) {                                                  \
      const int co = cx ^ (kk * 64);                                                  \
      _Pragma("unroll")                                                               \
      for (int mi = 0; mi < 4; ++mi) af[kk][mi] = *(const short8*)(aB + mi * 2048 + co); \
      _Pragma("unroll")                                                               \
      for (int nj = 0; nj < 4; ++nj) bf[kk][nj] = *(const short8*)(bB + nj * 2048 + co); \
    }                                                                                 \
  } while (0)

#define MFMA_ALL(af, bf)                                                              \
  do {                                                                                \
    _Pragma("unroll")                                                                 \
    for (int kk = 0; kk < 2; ++kk)                                                    \
      _Pragma("unroll")                                                               \
      for (int mi = 0; mi < 4; ++mi)                                                  \
        _Pragma("unroll")                                                             \
        for (int nj = 0; nj < 4; ++nj)                                                \
          acc[mi][nj] = __builtin_amdgcn_mfma_f32_16x16x32_bf16(af[kk][mi], bf[kk][nj], acc[mi][nj], 0, 0, 0); \
  } while (0)

  // prologue: stage tiles 0,1; land 0; read frags(0)
  STAGE(0, 0);
  STAGE(1, 1);
  asm volatile("s_waitcnt vmcnt(6)" ::: "memory");   // stage(0) landed
  __builtin_amdgcn_sched_barrier(0);
  __builtin_amdgcn_s_barrier();
  READ_FRAGS(afA, bfA, 0);
  asm volatile("s_waitcnt lgkmcnt(0)" ::: "memory");
  __builtin_amdgcn_sched_barrier(0);
  __builtin_amdgcn_s_barrier();                      // slot0 fully consumed
  // invariant entering each sub-iter: outstanding vmem = stage(next tile) = 6

  for (int t = 0; t < NT; t += 2) {
    // even: compute tile t (fragsA), stage t+2 -> slot0, read frags(t+1) from slot1
    if (t + 2 < NT) { STAGE(t + 2, 0); asm volatile("s_waitcnt vmcnt(6)" ::: "memory"); }
    else            { asm volatile("s_waitcnt vmcnt(0)" ::: "memory"); }
    __builtin_amdgcn_sched_barrier(0);
    __builtin_amdgcn_s_barrier();                    // stage(t+1) visible (slot1)
    READ_FRAGS(afB, bfB, 1);
    __builtin_amdgcn_sched_barrier(0);               // reads issued before MFMA
    __builtin_amdgcn_s_setprio(1);
    MFMA_ALL(afA, bfA);
    __builtin_amdgcn_s_setprio(0);
    asm volatile("s_waitcnt lgkmcnt(0)" ::: "memory");
    __builtin_amdgcn_sched_barrier(0);
    __builtin_amdgcn_s_barrier();                    // slot1 fully consumed

    // odd: compute tile t+1 (fragsB), stage t+3 -> slot1, read frags(t+2) from slot0
    if (t + 3 < NT) { STAGE(t + 3, 1); asm volatile("s_waitcnt vmcnt(6)" ::: "memory"); }
    else            { asm volatile("s_waitcnt vmcnt(0)" ::: "memory"); }
    __builtin_amdgcn_sched_barrier(0);
    __builtin_amdgcn_s_barrier();                    // stage(t+2) visible (slot0)
    if (t + 2 < NT) READ_FRAGS(afA, bfA, 0);
    __builtin_amdgcn_sched_barrier(0);
    __builtin_amdgcn_s_setprio(1);
    MFMA_ALL(afB, bfB);
    __builtin_amdgcn_s_setprio(0);
    asm volatile("s_waitcnt lgkmcnt(0)" ::: "memory");
    __builtin_amdgcn_sched_barrier(0);
    __builtin_amdgcn_s_barrier();                    // slot0 fully consumed
  }
#undef STAGE
#undef READ_FRAGS
#undef MFMA_ALL

  if constexpr (EPI == 0) {
    if (which < 2) {
      short* outb = (which == 0) ? qo : ko;
#pragma unroll
      for (int mi = 0; mi < 4; ++mi)
#pragma unroll
        for (int nj = 0; nj < 4; ++nj)
#pragma unroll
          for (int r = 0; r < 4; ++r) {
            int row = m0 + wr * 64 + mi * 16 + g * 4 + r;
            int col = wn0 + wc * 64 + nj * 16 + c;
            float v = acc[mi][nj][r];
            float other = __shfl_xor(v, 1);
            int pi = (col & (HDc - 1)) >> 1;
            int sp = row & (Sc - 1);
            float cv = ct[sp * 64 + pi], sv = st[sp * 64 + pi];
            v = ((col & 1) == 0) ? (v * cv - other * sv) : (other * sv + v * cv);
            int b_ = row >> 11, sq = row & (Sc - 1);
            int h_ = col >> 7, dd = col & (HDc - 1);
            outb[((size_t)(b_ * Hc + h_) * Sc + sq) * HDc + dd] = f2bf(v);
          }
    } else {
      // V^T store: vo[b][h][dd][s]
#pragma unroll
      for (int mi = 0; mi < 4; ++mi)
#pragma unroll
        for (int nj = 0; nj < 4; ++nj) {
          int row0 = m0 + wr * 64 + mi * 16 + g * 4;
          int col = wn0 + wc * 64 + nj * 16 + c;
          int b_ = row0 >> 11, sq0 = row0 & (Sc - 1);
          int h_ = col >> 7, dd = col & (HDc - 1);
          s16x4 pk;
#pragma unroll
          for (int r = 0; r < 4; ++r) pk[r] = f2bf(acc[mi][nj][r]);
          *(s16x4*)&vo[((size_t)(b_ * Hc + h_) * HDc + dd) * Sc + sq0] = pk;
        }
    }
  } else {
#pragma unroll
    for (int mi = 0; mi < 4; ++mi)
#pragma unroll
      for (int nj = 0; nj < 4; ++nj)
#pragma unroll
        for (int r = 0; r < 4; ++r) {
          int row = m0 + wr * 64 + mi * 16 + g * 4 + r;
          int col = wn0 + wc * 64 + nj * 16 + c;
          outf[(size_t)row * Dc + col] = acc[mi][nj][r];
        }
  }
}

// ---------------------------------------------------------------------------
// Flash causal attention (unchanged from round 4). 4 waves; Q-tile 64, KV 64.
// ---------------------------------------------------------------------------
DEV void stage_kv(const short* kh, const short* vth, int kv0,
                  short* Kb, short* Vb, int w, int tid) {
#pragma unroll
  for (int i = 0; i < 4; ++i) {                 // K: 1024 chunks, 16/row
    int L = i * 256 + tid;
    int row = L >> 4, p = L & 15;
    gload_lds16(kh + (size_t)(kv0 + row) * HDc + ((p ^ (row & 7)) * 8),
                (char*)Kb + i * 4096 + w * 1024);
  }
#pragma unroll
  for (int i = 0; i < 4; ++i) {                 // V^T: 1024 chunks, 8/row
    int L = i * 256 + tid;
    int row = L >> 3, p = L & 7;
    gload_lds16(vth + (size_t)row * Sc + kv0 + ((p ^ (row & 7)) * 8),
                (char*)Vb + i * 4096 + w * 1024);
  }
}

__global__ __launch_bounds__(256) void attn_kernel(
    const short* __restrict__ qb, const short* __restrict__ kb,
    const short* __restrict__ vtb, short* __restrict__ ob) {
  __shared__ short Kl[2][64 * 128];
  __shared__ short Vl[2][128 * 64];
  __shared__ short Pl[4 * 16 * 72];

  const int tid = threadIdx.x, lane = tid & 63, w = tid >> 6;
  const int g = lane >> 4, c = lane & 15;
  const int bh = blockIdx.y;
  const int b_ = bh >> 4, h_ = bh & 15;
  const short* qh = qb + (size_t)bh * Sc * HDc;
  const short* kh = kb + (size_t)bh * Sc * HDc;
  const short* vth = vtb + (size_t)bh * HDc * Sc;

  for (int pass = 0; pass < 2; ++pass) {
    const int qt = pass ? (31 - blockIdx.x) : blockIdx.x;
    const int q0 = qt * 64;

    short8 qf[4];
#pragma unroll
    for (int kc = 0; kc < 4; ++kc)
      qf[kc] = *(const short8*)&qh[(size_t)(q0 + w * 16 + c) * HDc + kc * 32 + g * 8];

    float mrow[4], lrow[4];
    f32x4 acc[8] = {};
#pragma unroll
    for (int r = 0; r < 4; ++r) { mrow[r] = -1e30f; lrow[r] = 0.f; }

    const int nt = qt + 1;
    int cur = 0;
    stage_kv(kh, vth, 0, Kl[0], Vl[0], w, tid);
    __syncthreads();

    for (int kvt = 0; kvt < nt; ++kvt) {
      if (kvt + 1 < nt)
        stage_kv(kh, vth, (kvt + 1) * 64, Kl[cur ^ 1], Vl[cur ^ 1], w, tid);

      // S = Q K^T (wave: 16 q-rows x 64 kv)
      f32x4 sacc[4];
#pragma unroll
      for (int kb_ = 0; kb_ < 4; ++kb_) {
        sacc[kb_] = (f32x4){0.f, 0.f, 0.f, 0.f};
#pragma unroll
        for (int kc = 0; kc < 4; ++kc) {
          short8 kf = *(const short8*)&Kl[cur][(kb_ * 16 + c) * 128 + (((kc * 4 + g) ^ (c & 7)) * 8)];
          sacc[kb_] = __builtin_amdgcn_mfma_f32_16x16x32_bf16(qf[kc], kf, sacc[kb_], 0, 0, 0);
        }
      }
      float p[4][4];
      const bool last = (kvt == qt);
      const int kv0 = kvt * 64;
#pragma unroll
      for (int kb_ = 0; kb_ < 4; ++kb_)
#pragma unroll
        for (int r = 0; r < 4; ++r) {
          float s = sacc[kb_][r] * ATTN_SCALE;
          if (last) {
            int qg = q0 + w * 16 + g * 4 + r;
            int kg = kv0 + kb_ * 16 + c;
            if (kg > qg) s = -1e30f;
          }
          p[kb_][r] = s;
        }
      // online softmax (row r at lanes sharing g; reduce across c)
      float scal[4];
#pragma unroll
      for (int r = 0; r < 4; ++r) {
        float v = fmaxf(fmaxf(p[0][r], p[1][r]), fmaxf(p[2][r], p[3][r]));
        v = fmaxf(v, __shfl_xor(v, 1));
        v = fmaxf(v, __shfl_xor(v, 2));
        v = fmaxf(v, __shfl_xor(v, 4));
        v = fmaxf(v, __shfl_xor(v, 8));
        float mn = fmaxf(mrow[r], v);
        scal[r] = __expf(mrow[r] - mn);
        mrow[r] = mn;
      }
#pragma unroll
      for (int r = 0; r < 4; ++r) {
        float acc_s = 0.f;
#pragma unroll
        for (int kb_ = 0; kb_ < 4; ++kb_) {
          p[kb_][r] = __expf(p[kb_][r] - mrow[r]);
          acc_s += p[kb_][r];
        }
        acc_s += __shfl_xor(acc_s, 1);
        acc_s += __shfl_xor(acc_s, 2);
        acc_s += __shfl_xor(acc_s, 4);
        acc_s += __shfl_xor(acc_s, 8);
        lrow[r] = lrow[r] * scal[r] + acc_s;
      }
#pragma unroll
      for (int db = 0; db < 8; ++db)
#pragma unroll
        for (int r = 0; r < 4; ++r) acc[db][r] *= scal[r];
      // P -> per-wave LDS (bf16), read back as A-frag
#pragma unroll
      for (int kb_ = 0; kb_ < 4; ++kb_)
#pragma unroll
        for (int r = 0; r < 4; ++r)
          Pl[w * 16 * 72 + (g * 4 + r) * 72 + kb_ * 16 + c] = f2bf(p[kb_][r]);
      short8 pa[2];
#pragma unroll
      for (int k2 = 0; k2 < 2; ++k2)
        pa[k2] = *(const short8*)&Pl[w * 16 * 72 + c * 72 + k2 * 32 + g * 8];
#pragma unroll
      for (int db = 0; db < 8; ++db)
#pragma unroll
        for (int k2 = 0; k2 < 2; ++k2) {
          short8 vf = *(const short8*)&Vl[cur][(db * 16 + c) * 64 + (((k2 * 4 + g) ^ (c & 7)) * 8)];
          acc[db] = __builtin_amdgcn_mfma_f32_16x16x32_bf16(pa[k2], vf, acc[db], 0, 0, 0);
        }
      __syncthreads();
      cur ^= 1;
    }

#pragma unroll
    for (int db = 0; db < 8; ++db)
#pragma unroll
      for (int r = 0; r < 4; ++r) {
        int qg = q0 + w * 16 + g * 4 + r;
        int d = db * 16 + c;
        float v = acc[db][r] / lrow[r];
        ob[((size_t)(b_ * Sc + qg)) * Dc + h_ * HDc + d] = f2bf(v);
      }
  }
}

extern "C" void kernel_launch(void* const* d_in, const int* in_sizes, int n_in,
                              void* d_out, int out_size, void* d_ws, size_t ws_size,
                              hipStream_t stream) {
  const float* x = (const float*)d_in[0];
  const float* wq = (const float*)d_in[1];
  const float* wk = (const float*)d_in[2];
  const float* wv = (const float*)d_in[3];
  const float* wo = (const float*)d_in[4];
  float* out = (float*)d_out;

  char* ws = (char*)d_ws;
  short* xb  = (short*)(ws + 0);              // [4096][2048] bf16 (reused as attn-out)
  short* wqb = (short*)(ws + 16777216);
  short* wkb = (short*)(ws + 25165824);
  short* wvb = (short*)(ws + 33554432);
  short* wob = (short*)(ws + 41943040);
  short* qb  = (short*)(ws + 50331648);       // [B,H,S,HD]
  short* kbf = (short*)(ws + 67108864);       // [B,H,S,HD]
  short* vtb = (short*)(ws + 83886080);       // [B,H,HD,S]  (transposed V)
  float* ct  = (float*)(ws + 100663296);      // [S][64]
  float* st  = (float*)(ws + 101187584);
  short* obuf = xb;                           // reuse x buffer for attention output

  cast_f32_bf16<<<Mc * Dc / 8 / 256, 256, 0, stream>>>(x, xb, Mc * Dc / 8);
  cast_f32_bf16<<<Dc * Dc / 8 / 256, 256, 0, stream>>>(wq, wqb, Dc * Dc / 8);
  cast_f32_bf16<<<Dc * Dc / 8 / 256, 256, 0, stream>>>(wk, wkb, Dc * Dc / 8);
  cast_f32_bf16<<<Dc * Dc / 8 / 256, 256, 0, stream>>>(wv, wvb, Dc * Dc / 8);
  cast_f32_bf16<<<Dc * Dc / 8 / 256, 256, 0, stream>>>(wo, wob, Dc * Dc / 8);
  rope_table<<<Sc * 64 / 256, 256, 0, stream>>>(ct, st);

  // QKV: N = 3*2048 over BN=256 -> 24 x-blocks; M=4096 over BM=128 -> 32 y-blocks
  gemm_pipe<0><<<dim3(24, 32), 512, 0, stream>>>(xb, wqb, wkb, wvb, qb, kbf, vtb, nullptr, ct, st);

  attn_kernel<<<dim3(Sc / 128, Bc * Hc), 256, 0, stream>>>(qb, kbf, vtb, obuf);

  // Out-proj: N = 2048 -> 8 x-blocks
  gemm_pipe<1><<<dim3(8, 32), 512, 0, stream>>>(obuf, wob, nullptr, nullptr,
                                                nullptr, nullptr, nullptr, out, ct, st);
}